// Round 6
// baseline (10795.742 us; speedup 1.0000x reference)
//
#include <hip/hip_runtime.h>

// ---------------- constants ----------------
#define NE 60000
#define NA 30000
#define E_EE 150000
#define E_EA 75000
#define E_AE 75000
#define SCALE 0.17677669529663689f   // 1/sqrt(32)

__device__ __forceinline__ float gelu_f(float x) {
  return 0.5f * x * (1.0f + erff(x * 0.7071067811865476f));
}

// ---------------- fused relation weights (all f32) ----------------
// Wkt[t][i][h*32+e] = sum_d Wkqv[i, 0*128 + h*32+d] * a_rel[t][h][d][e]
// Wvt[t][i][h*32+e] = sum_d Wkqv[i, 2*128 + h*32+d] * m_rel[t][h][d][e]
__global__ __launch_bounds__(256) void wrel_k(
    const float* __restrict__ Wk_e, const float* __restrict__ Wk_a,
    const float* __restrict__ bk_e, const float* __restrict__ bk_a,
    const float* __restrict__ a_rel, const float* __restrict__ m_rel,
    float* __restrict__ Wkt, float* __restrict__ Wvt,
    float* __restrict__ bkt, float* __restrict__ bvt) {
  int t = blockIdx.x;        // relation 0..2
  int part = blockIdx.y;     // 0: key (a_rel, col-block 0), 1: value (m_rel, col-block 256)
  const float* W = (t < 2) ? Wk_e : Wk_a;
  const float* bb = (t < 2) ? bk_e : bk_a;
  const float* A = (part ? m_rel : a_rel) + t * 4096;
  int coff = part ? 256 : 0;
  float* Wo = (part ? Wvt : Wkt) + t * 16384;
  float* bo = (part ? bvt : bkt) + t * 128;
  __shared__ float As[4096];
  for (int u = threadIdx.x; u < 4096; u += 256) As[u] = A[u];
  __syncthreads();
  for (int u = threadIdx.x; u < 16384; u += 256) {
    int i = u >> 7, c = u & 127;
    int hh = c >> 5, e = c & 31;
    const float* wr = W + i * 384 + coff + hh * 32;
    const float* ar = As + hh * 1024 + e;
    float acc = 0.f;
#pragma unroll
    for (int d = 0; d < 32; ++d) acc = fmaf(wr[d], ar[d * 32], acc);
    Wo[u] = acc;
  }
  if (threadIdx.x < 128) {
    int c = threadIdx.x, hh = c >> 5, e = c & 31;
    const float* br = bb + coff + hh * 32;
    const float* ar = As + hh * 1024 + e;
    float acc = 0.f;
#pragma unroll
    for (int d = 0; d < 32; ++d) acc = fmaf(br[d], ar[d * 32], acc);
    bo[c] = acc;
  }
}

// ---------------- row GEMM: one block = one row, y = act(x) @ W + b ----------------
// ACT: 0 none, 1 gelu(x).  EPI: 0 plain store, 1 relu store.
template <int ACT, int EPI>
__global__ __launch_bounds__(128) void rowgemm_k(
    const float* __restrict__ X, int ldx,
    const float* __restrict__ W, int ldw,
    const float* __restrict__ bias, int N,
    float* __restrict__ out, int ldo) {
  int row = blockIdx.x;
  int j = threadIdx.x;
  __shared__ float xs[128];
  {
    float v = X[(size_t)row * ldx + j];
    if (ACT == 1) v = gelu_f(v);
    xs[j] = v;
  }
  __syncthreads();
  float acc = bias ? bias[j] : 0.f;
  for (int k = 0; k < 128; ++k)
    acc = fmaf(xs[k], W[(size_t)k * ldw + j], acc);
  if (EPI == 1) acc = fmaxf(acc, 0.f);
  out[(size_t)row * ldo + j] = acc;
}

// ---------------- gated skip blend + gelu:  h = gelu(g*o + (1-g)*h) ----------------
__global__ __launch_bounds__(256) void blend_k(const float* __restrict__ o,
                                               float* __restrict__ h,
                                               const float* __restrict__ skipp, int n) {
  int i = blockIdx.x * 256 + threadIdx.x;
  if (i >= n) return;
  float g = 1.f / (1.f + expf(-*skipp));
  h[i] = gelu_f(g * o[i] + (1.f - g) * h[i]);
}

// ---------------- edge kernels (joint softmax per dst; logits O(1), no max-sub) ----
__global__ __launch_bounds__(256) void edge_logits_k(
    const float* __restrict__ q, const float* __restrict__ kt,
    const int* __restrict__ ei, int E, const float* __restrict__ p,
    float* __restrict__ out) {
  int idx = blockIdx.x * 256 + threadIdx.x;
  if (idx >= E * 4) return;
  int e = idx >> 2, h = idx & 3;
  int src = ei[e], dst = ei[E + e];
  const float* qr = q + (size_t)dst * 128 + h * 32;
  const float* kr = kt + (size_t)src * 128 + h * 32;
  float acc = 0.f;
#pragma unroll
  for (int u = 0; u < 32; ++u) acc = fmaf(qr[u], kr[u], acc);
  out[idx] = acc * SCALE * p[h];
}

__global__ __launch_bounds__(256) void seg_exp_k(float* __restrict__ logits,
                                                 const int* __restrict__ ei, int E,
                                                 float* __restrict__ s) {
  int idx = blockIdx.x * 256 + threadIdx.x;
  if (idx >= E * 4) return;
  int e = idx >> 2, h = idx & 3;
  int dst = ei[E + e];
  float w = expf(logits[idx]);
  logits[idx] = w;
  atomicAdd(&s[dst * 4 + h], w);
}

__global__ __launch_bounds__(256) void aggregate_k(
    const float* __restrict__ logits, const int* __restrict__ ei, int E,
    const float* __restrict__ s, const float* __restrict__ vt,
    float* __restrict__ outs) {
  int idx = blockIdx.x * 256 + threadIdx.x;
  if (idx >= E * 4) return;
  int e = idx >> 2, h = idx & 3;
  int src = ei[e], dst = ei[E + e];
  float w = logits[idx] / (s[dst * 4 + h] + 1e-16f);
  const float* vr = vt + (size_t)src * 128 + h * 32;
  float* o = outs + (size_t)dst * 128 + h * 32;
#pragma unroll
  for (int u = 0; u < 32; ++u) atomicAdd(o + u, w * vr[u]);
}

// ---------------- LayerNorm (row=128): out = LN(alpha*A + beta*B)*g + b ----------------
__global__ __launch_bounds__(128) void ln_k(const float* __restrict__ A,
                                            const float* __restrict__ B, float alpha,
                                            float beta, const float* __restrict__ g,
                                            const float* __restrict__ b,
                                            float* __restrict__ out, int relu) {
  int row = blockIdx.x;
  int t = threadIdx.x;
  float v = alpha * A[(size_t)row * 128 + t];
  if (B) v += beta * B[(size_t)row * 128 + t];
  float s1 = v, s2 = v * v;
#pragma unroll
  for (int m = 32; m > 0; m >>= 1) {
    s1 += __shfl_xor(s1, m, 64);
    s2 += __shfl_xor(s2, m, 64);
  }
  __shared__ float r1[2], r2[2];
  int w = t >> 6;
  if ((t & 63) == 0) { r1[w] = s1; r2[w] = s2; }
  __syncthreads();
  float S1 = r1[0] + r1[1], S2 = r2[0] + r2[1];
  float mu = S1 * (1.f / 128.f);
  float var = S2 * (1.f / 128.f) - mu * mu;
  float rr = rsqrtf(fmaxf(var, 0.f) + 1e-5f);
  float o = (v - mu) * rr * g[t] + b[t];
  if (relu) o = fmaxf(o, 0.f);
  out[(size_t)row * 128 + t] = o;
}

// ---------------- fused K,V projection + kvs outer product + ksum + ssq_k ----------
// kvs[h][m][d] = sum_n k[n,h,m]*v[n,h,d];  k,v computed on the fly from z0 (f32)
__global__ __launch_bounds__(256, 2) void kvsfused_k(
    const float* __restrict__ z0, const float* __restrict__ Wk,
    const float* __restrict__ bk, const float* __restrict__ Wv,
    const float* __restrict__ bv, float* __restrict__ kvs, float* __restrict__ ksum,
    float* __restrict__ ssqk, int N, int chunk) {
  int h = blockIdx.y;
  int n0 = blockIdx.x * chunk;
  int n1 = n0 + chunk; if (n1 > N) n1 = N;
  __shared__ float zs[8][132];
  __shared__ float ks[8][132];
  __shared__ float vs[8][132];
  float acc[8][8];
#pragma unroll
  for (int i = 0; i < 8; ++i)
#pragma unroll
    for (int j = 0; j < 8; ++j) acc[i][j] = 0.f;
  float ksloc = 0.f, sql = 0.f;
  int ti = threadIdx.x >> 4, tj = threadIdx.x & 15;
  for (int n = n0; n < n1; n += 8) {
    __syncthreads();
    for (int u = threadIdx.x; u < 1024; u += 256) {
      int ni = u >> 7, c = u & 127;
      int ng = n + ni;
      zs[ni][c] = (ng < n1) ? z0[(size_t)ng * 128 + c] : 0.f;
    }
    __syncthreads();
    // compute k,v tiles: 2048 outputs, 8 per thread
#pragma unroll
    for (int r = 0; r < 8; ++r) {
      int u = threadIdx.x + 256 * r;
      int which = u >> 10;            // 0: k-tile, 1: v-tile
      int ni = (u >> 7) & 7, j = u & 127;
      const float* Wp = which ? Wv : Wk;
      const float* bp = which ? bv : bk;
      float a = 0.f;
      if (n + ni < n1) {
        a = bp[h * 128 + j];
        for (int k = 0; k < 128; ++k)
          a = fmaf(zs[ni][k], Wp[(size_t)k * 512 + h * 128 + j], a);
        if (!which) sql += a * a;
      }
      (which ? vs : ks)[ni][j] = a;
    }
    __syncthreads();
#pragma unroll
    for (int ni = 0; ni < 8; ++ni) {
      float kk[8], vv[8];
#pragma unroll
      for (int u = 0; u < 8; ++u) { kk[u] = ks[ni][ti * 8 + u]; vv[u] = vs[ni][tj * 8 + u]; }
#pragma unroll
      for (int i = 0; i < 8; ++i)
#pragma unroll
        for (int j = 0; j < 8; ++j) acc[i][j] = fmaf(kk[i], vv[j], acc[i][j]);
      if (threadIdx.x < 128) ksloc += ks[ni][threadIdx.x];
    }
  }
#pragma unroll
  for (int i = 0; i < 8; ++i)
#pragma unroll
    for (int j = 0; j < 8; ++j)
      atomicAdd(&kvs[((size_t)h * 128 + ti * 8 + i) * 128 + tj * 8 + j], acc[i][j]);
  if (threadIdx.x < 128) atomicAdd(&ksum[h * 128 + threadIdx.x], ksloc);
  __syncthreads();
  float* zf = &zs[0][0];
  zf[threadIdx.x] = sql;
  __syncthreads();
  if (threadIdx.x == 0) {
    float t = 0.f;
    for (int i = 0; i < 256; ++i) t += zf[i];
    atomicAdd(ssqk, t);
  }
}

// ---------------- ssq_q = sum |z0@Wq + bq|^2 (Q never materialized) ----------------
__global__ __launch_bounds__(128) void ssqq_k(const float* __restrict__ z0,
                                              const float* __restrict__ Wq,
                                              const float* __restrict__ bq,
                                              float* __restrict__ ssqq, int N) {
  int row = blockIdx.x, j = threadIdx.x;
  __shared__ float zs[128];
  zs[j] = z0[(size_t)row * 128 + j];
  __syncthreads();
  float s = 0.f;
#pragma unroll
  for (int h = 0; h < 4; ++h) {
    float a = bq[h * 128 + j];
    for (int k = 0; k < 128; ++k)
      a = fmaf(zs[k], Wq[(size_t)k * 512 + h * 128 + j], a);
    s += a * a;
  }
  __syncthreads();
  zs[j] = s;
  __syncthreads();
  if (j == 0) {
    float t = 0.f;
    for (int i = 0; i < 128; ++i) t += zs[i];
    atomicAdd(ssqq, t);
  }
}

// ---------------- attn row: recompute q,v; den fused; apply ----------------
__global__ __launch_bounds__(128) void attnrow_k(const float* __restrict__ z0,
                                                 const float* __restrict__ Wq,
                                                 const float* __restrict__ bq,
                                                 const float* __restrict__ Wv,
                                                 const float* __restrict__ bv,
                                                 const float* __restrict__ kvs,
                                                 const float* __restrict__ ksum,
                                                 const float* __restrict__ ssqq,
                                                 const float* __restrict__ ssqk,
                                                 float* __restrict__ attn, int N) {
  int n = blockIdx.x, j = threadIdx.x;
  __shared__ float zs[128];
  __shared__ float qs[512];
  __shared__ float dpart[512];
  __shared__ float den[4];
  __shared__ float fsh;
  zs[j] = z0[(size_t)n * 128 + j];
  if (j == 0) fsh = 1.0f / (sqrtf(*ssqq) * sqrtf(*ssqk));
  __syncthreads();
#pragma unroll
  for (int h = 0; h < 4; ++h) {
    float a = bq[h * 128 + j];
    for (int k = 0; k < 128; ++k)
      a = fmaf(zs[k], Wq[(size_t)k * 512 + h * 128 + j], a);
    qs[h * 128 + j] = a;
    dpart[h * 128 + j] = a * ksum[h * 128 + j];
  }
  __syncthreads();
  if (j < 4) {
    float t = 0.f;
    for (int i = 0; i < 128; ++i) t += dpart[j * 128 + i];
    den[j] = t * fsh + 60000.0f;
  }
  __syncthreads();
  float out = 0.f;
#pragma unroll
  for (int h = 0; h < 4; ++h) {
    float acc = 0.f;
    const float* kp = kvs + (size_t)h * 16384 + j;
    const float* qp = qs + h * 128;
    for (int m = 0; m < 128; ++m) acc = fmaf(qp[m], kp[(size_t)m * 128], acc);
    float v = bv[h * 128 + j];
    for (int k = 0; k < 128; ++k)
      v = fmaf(zs[k], Wv[(size_t)k * 512 + h * 128 + j], v);
    out += (acc * fsh + 60000.0f * v) / den[h];
  }
  attn[(size_t)n * 128 + j] = 0.25f * out;
}

// ---------------- host ----------------
extern "C" void kernel_launch(void* const* d_in, const int* in_sizes, int n_in,
                              void* d_out, int out_size, void* d_ws, size_t ws_size,
                              hipStream_t stream) {
  const float* x_ent = (const float*)d_in[0];
  const float* x_att = (const float*)d_in[1];
  const float* Wkqv_e = (const float*)d_in[2];
  const float* bkqv_e = (const float*)d_in[3];
  const float* Wkqv_a = (const float*)d_in[4];
  const float* bkqv_a = (const float*)d_in[5];
  const float* Wout_e = (const float*)d_in[6];
  const float* bout_e = (const float*)d_in[7];
  const float* Wout_a = (const float*)d_in[8];
  const float* bout_a = (const float*)d_in[9];
  const float* skip_e = (const float*)d_in[10];
  const float* skip_a = (const float*)d_in[11];
  const float* a_rel = (const float*)d_in[12];
  const float* m_rel = (const float*)d_in[13];
  const float* p_rel = (const float*)d_in[14];
  const float* ln_ent_g = (const float*)d_in[15];
  const float* ln_ent_b = (const float*)d_in[16];
  const float* sg_fc_W = (const float*)d_in[17];
  const float* sg_fc_b = (const float*)d_in[18];
  const float* sg_ln0_g = (const float*)d_in[19];
  const float* sg_ln0_b = (const float*)d_in[20];
  const float* sg_Wq = (const float*)d_in[21];
  const float* sg_bq = (const float*)d_in[22];
  const float* sg_Wk = (const float*)d_in[23];
  const float* sg_bk = (const float*)d_in[24];
  const float* sg_Wv = (const float*)d_in[25];
  const float* sg_bv = (const float*)d_in[26];
  const float* sg_ln1_g = (const float*)d_in[27];
  const float* sg_ln1_b = (const float*)d_in[28];
  const float* proj_W1 = (const float*)d_in[29];
  const float* proj_b1 = (const float*)d_in[30];
  const float* proj_W2 = (const float*)d_in[31];
  const float* proj_b2 = (const float*)d_in[32];
  const int* ei_ee = (const int*)d_in[33];
  const int* ei_ea = (const int*)d_in[34];
  const int* ei_ae = (const int*)d_in[35];

  char* ws = (char*)d_ws;
  // ---- workspace layout (bytes), total ~206.6 MB (ws_size >= 215.7 MB verified R5) ----
  const size_t O_HE = 0;                         // NE*128 f32
  const size_t O_HA = 30720000;                  // NA*128 f32
  const size_t O_Z0 = 46080000;                  // NE*128 f32
  const size_t O_WKT = 76800000;                 // 3*16384 f32
  const size_t O_WVT = 76996608;
  const size_t O_BKT = 77193216;
  const size_t O_BVT = 77194752;
  const size_t O_KVS = 77196288;                 // kvs(262144)+ksum(2048)+ssq(64)
  const size_t O_UN = 77460544;                  // union region (129.12 MB)
  // HGT view:
  float* q_e = (float*)(ws + O_UN);
  float* q_a = (float*)(ws + O_UN + 30720000);
  float* Tbuf = (float*)(ws + O_UN + 46080000);
  float* outs_e = (float*)(ws + O_UN + 76800000);
  float* outs_a = (float*)(ws + O_UN + 107520000);
  float* logits = (float*)(ws + O_UN + 122880000);
  float* s_e = (float*)(ws + O_UN + 127680000);
  float* s_a = (float*)(ws + O_UN + 128640000);
  const size_t ZERO_OFF = O_UN + 76800000;
  const size_t ZERO_BYTES = 52320000;            // outs_e..s_a
  // SG view:
  float* attn = (float*)(ws + O_UN);             // NE*128 f32
  float* tmp = (float*)(ws + O_UN + 30720000);   // NE*128 f32

  float* h_e = (float*)(ws + O_HE);
  float* h_a = (float*)(ws + O_HA);
  float* z0 = (float*)(ws + O_Z0);
  float* Wkt = (float*)(ws + O_WKT);
  float* Wvt = (float*)(ws + O_WVT);
  float* bkt = (float*)(ws + O_BKT);
  float* bvt = (float*)(ws + O_BVT);
  float* kvs = (float*)(ws + O_KVS);
  float* ksum = (float*)(ws + O_KVS + 262144);
  float* ssq_q = (float*)(ws + O_KVS + 262144 + 2048);
  float* ssq_k = ssq_q + 1;

  // copy inputs (f32) into mutable h buffers
  hipMemcpyAsync(h_e, x_ent, (size_t)NE * 128 * 4, hipMemcpyDeviceToDevice, stream);
  hipMemcpyAsync(h_a, x_att, (size_t)NA * 128 * 4, hipMemcpyDeviceToDevice, stream);

  const int* eis[3] = {ei_ee, ei_ea, ei_ae};
  const int Es[3] = {E_EE, E_EA, E_AE};
  const size_t offs[3] = {0, (size_t)E_EE * 4, (size_t)(E_EE + E_EA) * 4};
  float* hsrc[3]; int Nsrc[3]; float* qdst[3]; float* sdst[3]; float* odst[3];

  for (int l = 0; l < 2; ++l) {
    const float* Wke = Wkqv_e + (size_t)l * 49152;
    const float* Wka = Wkqv_a + (size_t)l * 49152;
    const float* bke = bkqv_e + (size_t)l * 384;
    const float* bka = bkqv_a + (size_t)l * 384;

    hsrc[0] = h_e; hsrc[1] = h_e; hsrc[2] = h_a;
    Nsrc[0] = NE; Nsrc[1] = NE; Nsrc[2] = NA;
    qdst[0] = q_e; qdst[1] = q_a; qdst[2] = q_e;
    sdst[0] = s_e; sdst[1] = s_a; sdst[2] = s_e;
    odst[0] = outs_e; odst[1] = outs_a; odst[2] = outs_e;

    wrel_k<<<dim3(3, 2), 256, 0, stream>>>(Wke, Wka, bke, bka,
                                           a_rel + (size_t)l * 12288,
                                           m_rel + (size_t)l * 12288, Wkt, Wvt, bkt, bvt);
    // q projections (cols 128..255 of Wkqv)
    rowgemm_k<0, 0><<<NE, 128, 0, stream>>>(h_e, 128, Wke + 128, 384, bke + 128, NE,
                                            q_e, 128);
    rowgemm_k<0, 0><<<NA, 128, 0, stream>>>(h_a, 128, Wka + 128, 384, bka + 128, NA,
                                            q_a, 128);
    hipMemsetAsync(ws + ZERO_OFF, 0, ZERO_BYTES, stream);

    for (int t = 0; t < 3; ++t) {
      rowgemm_k<0, 0><<<Nsrc[t], 128, 0, stream>>>(hsrc[t], 128, Wkt + t * 16384, 128,
                                                   bkt + t * 128, Nsrc[t], Tbuf, 128);
      edge_logits_k<<<(Es[t] * 4 + 255) / 256, 256, 0, stream>>>(
          qdst[t], Tbuf, eis[t], Es[t], p_rel + (size_t)(l * 3 + t) * 4, logits + offs[t]);
    }
    for (int t = 0; t < 3; ++t)
      seg_exp_k<<<(Es[t] * 4 + 255) / 256, 256, 0, stream>>>(logits + offs[t], eis[t],
                                                             Es[t], sdst[t]);
    for (int t = 0; t < 3; ++t) {
      rowgemm_k<0, 0><<<Nsrc[t], 128, 0, stream>>>(hsrc[t], 128, Wvt + t * 16384, 128,
                                                   bvt + t * 128, Nsrc[t], Tbuf, 128);
      aggregate_k<<<(Es[t] * 4 + 255) / 256, 256, 0, stream>>>(
          logits + offs[t], eis[t], Es[t], sdst[t], Tbuf, odst[t]);
    }
    // out proj (gelu on aggregated msg) into q regions (dead now)
    rowgemm_k<1, 0><<<NE, 128, 0, stream>>>(outs_e, 128, Wout_e + (size_t)l * 16384, 128,
                                            bout_e + (size_t)l * 128, NE, q_e, 128);
    rowgemm_k<1, 0><<<NA, 128, 0, stream>>>(outs_a, 128, Wout_a + (size_t)l * 16384, 128,
                                            bout_a + (size_t)l * 128, NA, q_a, 128);
    blend_k<<<(NE * 128 + 255) / 256, 256, 0, stream>>>(q_e, h_e, skip_e + l, NE * 128);
    blend_k<<<(NA * 128 + 255) / 256, 256, 0, stream>>>(q_a, h_a, skip_a + l, NA * 128);
  }

  // -------- SGFormer --------
  rowgemm_k<0, 0><<<NE, 128, 0, stream>>>(h_e, 128, sg_fc_W, 128, sg_fc_b, NE, tmp, 128);
  ln_k<<<NE, 128, 0, stream>>>(tmp, nullptr, 1.f, 0.f, sg_ln0_g, sg_ln0_b, z0, 1);
  hipMemsetAsync(ws + O_KVS, 0, 264256, stream);
  kvsfused_k<<<dim3(128, 4), 256, 0, stream>>>(z0, sg_Wk, sg_bk, sg_Wv, sg_bv, kvs, ksum,
                                               ssq_k, NE, 469);
  ssqq_k<<<NE, 128, 0, stream>>>(z0, sg_Wq, sg_bq, ssq_q, NE);
  attnrow_k<<<NE, 128, 0, stream>>>(z0, sg_Wq, sg_bq, sg_Wv, sg_bv, kvs, ksum, ssq_q,
                                    ssq_k, attn, NE);
  ln_k<<<NE, 128, 0, stream>>>(attn, z0, 0.5f, 0.5f, sg_ln1_g, sg_ln1_b, attn, 0);
  ln_k<<<NE, 128, 0, stream>>>(h_e, attn, 0.9f, 0.1f, ln_ent_g, ln_ent_b, attn, 0);
  // projector MLP
  rowgemm_k<0, 1><<<NE, 128, 0, stream>>>(attn, 128, proj_W1, 128, proj_b1, NE, tmp, 128);
  rowgemm_k<0, 0><<<NE, 128, 0, stream>>>(tmp, 128, proj_W2, 128, proj_b2, NE,
                                          (float*)d_out, 128);
}

// Round 7
// 6825.120 us; speedup vs baseline: 1.5818x; 1.5818x over previous
//
#include <hip/hip_runtime.h>

// ---------------- constants ----------------
#define NE 60000
#define NA 30000
#define E_EE 150000
#define E_EA 75000
#define E_AE 75000
#define SCALE 0.17677669529663689f   // 1/sqrt(32)

__device__ __forceinline__ float bf2f(unsigned short u) {
  return __uint_as_float(((unsigned)u) << 16);
}
__device__ __forceinline__ unsigned short f2bf(float f) {
  unsigned u = __float_as_uint(f);
  u = u + 0x7FFFu + ((u >> 16) & 1u);   // RNE
  return (unsigned short)(u >> 16);
}
__device__ __forceinline__ float ldc(const float* p) { return *p; }
__device__ __forceinline__ float ldc(const unsigned short* p) { return bf2f(*p); }
__device__ __forceinline__ float gelu_f(float x) {
  return 0.5f * x * (1.0f + erff(x * 0.7071067811865476f));
}

// ---------------- fused relation weights (all f32) ----------------
__global__ __launch_bounds__(256) void wrel_k(
    const float* __restrict__ Wk_e, const float* __restrict__ Wk_a,
    const float* __restrict__ bk_e, const float* __restrict__ bk_a,
    const float* __restrict__ a_rel, const float* __restrict__ m_rel,
    float* __restrict__ Wkt, float* __restrict__ Wvt,
    float* __restrict__ bkt, float* __restrict__ bvt) {
  int t = blockIdx.x;        // relation 0..2
  int part = blockIdx.y;     // 0: key (a_rel, cols 0..127), 1: value (m_rel, cols 256..)
  const float* W = (t < 2) ? Wk_e : Wk_a;
  const float* bb = (t < 2) ? bk_e : bk_a;
  const float* A = (part ? m_rel : a_rel) + t * 4096;
  int coff = part ? 256 : 0;
  float* Wo = (part ? Wvt : Wkt) + t * 16384;
  float* bo = (part ? bvt : bkt) + t * 128;
  __shared__ float As[4096];
  for (int u = threadIdx.x; u < 4096; u += 256) As[u] = A[u];
  __syncthreads();
  for (int u = threadIdx.x; u < 16384; u += 256) {
    int i = u >> 7, c = u & 127;
    int hh = c >> 5, e = c & 31;
    const float* wr = W + i * 384 + coff + hh * 32;
    const float* ar = As + hh * 1024 + e;
    float acc = 0.f;
#pragma unroll
    for (int d = 0; d < 32; ++d) acc = fmaf(wr[d], ar[d * 32], acc);
    Wo[u] = acc;
  }
  if (threadIdx.x < 128) {
    int c = threadIdx.x, hh = c >> 5, e = c & 31;
    const float* br = bb + coff + hh * 32;
    const float* ar = As + hh * 1024 + e;
    float acc = 0.f;
#pragma unroll
    for (int d = 0; d < 32; ++d) acc = fmaf(br[d], ar[d * 32], acc);
    bo[c] = acc;
  }
}

// ---------------- tiled GEMM: 32 rows x 128 cols per block, 256 threads -------------
// ACT: 0 none, 1 gelu(X).
// EPI: 0 f32 store; 1 relu f32 store; 2 bf16 store (+ atomic ssq if ssq!=null);
//      3 blend: fout = gelu(g*acc + (1-g)*fout), g = sigmoid(*skipp)  (in-place)
// col-block offset = blockIdx.y*128 applied to W, bias, and output.
template <int ACT, int EPI>
__global__ __launch_bounds__(256) void gemm32_k(
    const float* __restrict__ X, int ldx,
    const float* __restrict__ W, int ldw,
    const float* __restrict__ bias, int N,
    float* __restrict__ fout, unsigned short* __restrict__ bout, int ldo,
    const float* __restrict__ skipp, float* __restrict__ ssq) {
  __shared__ float Ws[64 * 128];
  __shared__ float Xs[32 * 132];
  const int tid = threadIdx.x;
  const int ct = tid & 31, rt = tid >> 5;
  const int row0 = blockIdx.x * 32;
  const int cb = blockIdx.y * 128;

  // stage X tile
  for (int u = tid; u < 1024; u += 256) {
    int r = u >> 5, c = (u & 31) << 2;
    int rg = row0 + r;
    if (rg >= N) rg = N - 1;
    float4 v = *reinterpret_cast<const float4*>(X + (size_t)rg * ldx + c);
    if (ACT == 1) {
      v.x = gelu_f(v.x); v.y = gelu_f(v.y); v.z = gelu_f(v.z); v.w = gelu_f(v.w);
    }
    *reinterpret_cast<float4*>(&Xs[r * 132 + c]) = v;
  }

  float acc[4][4];
  {
    float bc[4] = {0.f, 0.f, 0.f, 0.f};
    if (bias) {
#pragma unroll
      for (int j = 0; j < 4; ++j) bc[j] = bias[cb + (ct << 2) + j];
    }
#pragma unroll
    for (int i = 0; i < 4; ++i)
#pragma unroll
      for (int j = 0; j < 4; ++j) acc[i][j] = bc[j];
  }

  for (int kk = 0; kk < 2; ++kk) {
    __syncthreads();
    for (int u = tid; u < 2048; u += 256) {
      int r = u >> 5, c = (u & 31) << 2;
      *reinterpret_cast<float4*>(&Ws[r * 128 + c]) =
          *reinterpret_cast<const float4*>(W + (size_t)(kk * 64 + r) * ldw + cb + c);
    }
    __syncthreads();
#pragma unroll 4
    for (int k = 0; k < 64; k += 4) {
      float w[4][4];
#pragma unroll
      for (int dk = 0; dk < 4; ++dk)
        *reinterpret_cast<float4*>(w[dk]) =
            *reinterpret_cast<const float4*>(&Ws[(k + dk) * 128 + (ct << 2)]);
#pragma unroll
      for (int i = 0; i < 4; ++i) {
        float xv[4];
        *reinterpret_cast<float4*>(xv) =
            *reinterpret_cast<const float4*>(&Xs[(rt * 4 + i) * 132 + kk * 64 + k]);
#pragma unroll
        for (int dk = 0; dk < 4; ++dk)
#pragma unroll
          for (int j = 0; j < 4; ++j) acc[i][j] = fmaf(xv[dk], w[dk][j], acc[i][j]);
      }
    }
  }

  const int colb = cb + (ct << 2);
  if (EPI == 0 || EPI == 1) {
#pragma unroll
    for (int i = 0; i < 4; ++i) {
      int rg = row0 + rt * 4 + i;
      if (rg < N) {
        float4 v = make_float4(acc[i][0], acc[i][1], acc[i][2], acc[i][3]);
        if (EPI == 1) {
          v.x = fmaxf(v.x, 0.f); v.y = fmaxf(v.y, 0.f);
          v.z = fmaxf(v.z, 0.f); v.w = fmaxf(v.w, 0.f);
        }
        *reinterpret_cast<float4*>(fout + (size_t)rg * ldo + colb) = v;
      }
    }
  } else if (EPI == 2) {
    float loc = 0.f;
#pragma unroll
    for (int i = 0; i < 4; ++i) {
      int rg = row0 + rt * 4 + i;
      if (rg < N) {
        ushort4 s;
        s.x = f2bf(acc[i][0]); s.y = f2bf(acc[i][1]);
        s.z = f2bf(acc[i][2]); s.w = f2bf(acc[i][3]);
        *reinterpret_cast<ushort4*>(bout + (size_t)rg * ldo + colb) = s;
        loc += acc[i][0] * acc[i][0] + acc[i][1] * acc[i][1] +
               acc[i][2] * acc[i][2] + acc[i][3] * acc[i][3];
      }
    }
    if (ssq) {
      __syncthreads();
      Xs[tid] = loc;
      __syncthreads();
      if (tid < 128) Xs[tid] += Xs[tid + 128];
      __syncthreads();
      if (tid < 64) {
        float v = Xs[tid] + Xs[tid + 64];
#pragma unroll
        for (int m = 32; m > 0; m >>= 1) v += __shfl_down(v, m, 64);
        if (tid == 0) atomicAdd(ssq, v);
      }
    }
  } else {  // EPI == 3
    float g = 1.f / (1.f + expf(-*skipp));
    float g1 = 1.f - g;
#pragma unroll
    for (int i = 0; i < 4; ++i) {
      int rg = row0 + rt * 4 + i;
      if (rg < N) {
        float4 old = *reinterpret_cast<const float4*>(fout + (size_t)rg * ldo + colb);
        float4 v;
        v.x = gelu_f(g * acc[i][0] + g1 * old.x);
        v.y = gelu_f(g * acc[i][1] + g1 * old.y);
        v.z = gelu_f(g * acc[i][2] + g1 * old.z);
        v.w = gelu_f(g * acc[i][3] + g1 * old.w);
        *reinterpret_cast<float4*>(fout + (size_t)rg * ldo + colb) = v;
      }
    }
  }
}

// ---------------- fused edge logits + exp + denominator accumulation ----------------
__global__ __launch_bounds__(256) void edge_w_k(
    const float* __restrict__ q, const float* __restrict__ kt,
    const int* __restrict__ ei, int E, const float* __restrict__ p,
    float* __restrict__ wout, float* __restrict__ s) {
  int idx = blockIdx.x * 256 + threadIdx.x;
  if (idx >= E * 4) return;
  int e = idx >> 2, h = idx & 3;
  int src = ei[e], dst = ei[E + e];
  const float* qr = q + (size_t)dst * 128 + h * 32;
  const float* kr = kt + (size_t)src * 128 + h * 32;
  float acc = 0.f;
#pragma unroll
  for (int u = 0; u < 32; ++u) acc = fmaf(qr[u], kr[u], acc);
  float w = expf(acc * SCALE * p[h]);
  wout[idx] = w;
  atomicAdd(&s[dst * 4 + h], w);
}

__global__ __launch_bounds__(256) void aggregate_k(
    const float* __restrict__ wbuf, const int* __restrict__ ei, int E,
    const float* __restrict__ s, const float* __restrict__ vt,
    float* __restrict__ outs) {
  int idx = blockIdx.x * 256 + threadIdx.x;
  if (idx >= E * 4) return;
  int e = idx >> 2, h = idx & 3;
  int src = ei[e], dst = ei[E + e];
  float w = wbuf[idx] / (s[dst * 4 + h] + 1e-16f);
  const float* vr = vt + (size_t)src * 128 + h * 32;
  float* o = outs + (size_t)dst * 128 + h * 32;
#pragma unroll
  for (int u = 0; u < 32; ++u) atomicAdd(o + u, w * vr[u]);
}

// ---------------- LayerNorm (row=128): out = LN(alpha*A + beta*B)*g + b -------------
template <typename AT, typename BT>
__global__ __launch_bounds__(128) void ln_k(const AT* __restrict__ A,
                                            const BT* __restrict__ B, float alpha,
                                            float beta, const float* __restrict__ g,
                                            const float* __restrict__ b,
                                            float* __restrict__ out, int relu) {
  int row = blockIdx.x;
  int t = threadIdx.x;
  float v = alpha * ldc(A + (size_t)row * 128 + t);
  if (B) v += beta * ldc(B + (size_t)row * 128 + t);
  float s1 = v, s2 = v * v;
#pragma unroll
  for (int m = 32; m > 0; m >>= 1) {
    s1 += __shfl_xor(s1, m, 64);
    s2 += __shfl_xor(s2, m, 64);
  }
  __shared__ float r1[2], r2[2];
  int w = t >> 6;
  if ((t & 63) == 0) { r1[w] = s1; r2[w] = s2; }
  __syncthreads();
  float S1 = r1[0] + r1[1], S2 = r2[0] + r2[1];
  float mu = S1 * (1.f / 128.f);
  float var = S2 * (1.f / 128.f) - mu * mu;
  float rr = rsqrtf(fmaxf(var, 0.f) + 1e-5f);
  float o = (v - mu) * rr * g[t] + b[t];
  if (relu) o = fmaxf(o, 0.f);
  out[(size_t)row * 128 + t] = o;
}

// ---------------- kvs[h][m][d] = sum_n K[n,h,m]*V[n,h,d]; ksum[h][m] ----------------
__global__ __launch_bounds__(256) void kvsred_k(const unsigned short* __restrict__ Kb,
                                                const unsigned short* __restrict__ Vb,
                                                float* __restrict__ kvs,
                                                float* __restrict__ ksum, int N, int chunk) {
  int h = blockIdx.y;
  int n0 = blockIdx.x * chunk;
  int n1 = n0 + chunk; if (n1 > N) n1 = N;
  __shared__ float ks[8][132];
  __shared__ float vs[8][132];
  float acc[8][8];
#pragma unroll
  for (int i = 0; i < 8; ++i)
#pragma unroll
    for (int j = 0; j < 8; ++j) acc[i][j] = 0.f;
  float ksloc = 0.f;
  int ti = threadIdx.x >> 4, tj = threadIdx.x & 15;
  for (int n = n0; n < n1; n += 8) {
    __syncthreads();
    for (int u = threadIdx.x; u < 2048; u += 256) {
      int which = u >> 10;
      int ni = (u >> 7) & 7, c = u & 127;
      int ng = n + ni;
      float val = 0.f;
      if (ng < n1)
        val = bf2f((which ? Vb : Kb)[(size_t)ng * 512 + h * 128 + c]);
      (which ? vs : ks)[ni][c] = val;
    }
    __syncthreads();
#pragma unroll
    for (int ni = 0; ni < 8; ++ni) {
      float kk[8], vv[8];
#pragma unroll
      for (int u = 0; u < 8; ++u) { kk[u] = ks[ni][ti * 8 + u]; vv[u] = vs[ni][tj * 8 + u]; }
#pragma unroll
      for (int i = 0; i < 8; ++i)
#pragma unroll
        for (int j = 0; j < 8; ++j) acc[i][j] = fmaf(kk[i], vv[j], acc[i][j]);
      if (threadIdx.x < 128) ksloc += ks[ni][threadIdx.x];
    }
  }
#pragma unroll
  for (int i = 0; i < 8; ++i)
#pragma unroll
    for (int j = 0; j < 8; ++j)
      atomicAdd(&kvs[((size_t)h * 128 + ti * 8 + i) * 128 + tj * 8 + j], acc[i][j]);
  if (threadIdx.x < 128) atomicAdd(&ksum[h * 128 + threadIdx.x], ksloc);
}

// ---------------- SG attention apply: 32-row tile, kvs[h] in LDS, den fused ---------
__global__ __launch_bounds__(256) void sgapply_k(const unsigned short* __restrict__ Qb,
                                                 const unsigned short* __restrict__ Vb,
                                                 const float* __restrict__ kvs,
                                                 const float* __restrict__ ksum,
                                                 const float* __restrict__ ssqq,
                                                 const float* __restrict__ ssqk,
                                                 unsigned short* __restrict__ attnb) {
  __shared__ float Qs[32 * 132];
  __shared__ float Ws[64 * 128];
  __shared__ float dred[32][9];
  __shared__ float den_s[32];
  __shared__ float fsh;
  const int tid = threadIdx.x;
  const int ct = tid & 31, rt = tid >> 5;
  const int row0 = blockIdx.x * 32;
  if (tid == 0) fsh = 1.0f / (sqrtf(*ssqq) * sqrtf(*ssqk));
  float out[4][4];
#pragma unroll
  for (int i = 0; i < 4; ++i)
#pragma unroll
    for (int j = 0; j < 4; ++j) out[i][j] = 0.f;

  for (int h = 0; h < 4; ++h) {
    __syncthreads();
    // stage Q head-tile (bf16 -> f32)
    for (int u = tid; u < 1024; u += 256) {
      int r = u >> 5, c = (u & 31) << 2;
      ushort4 q4 = *reinterpret_cast<const ushort4*>(
          Qb + (size_t)(row0 + r) * 512 + h * 128 + c);
      float4 v = make_float4(bf2f(q4.x), bf2f(q4.y), bf2f(q4.z), bf2f(q4.w));
      *reinterpret_cast<float4*>(&Qs[r * 132 + c]) = v;
    }
    __syncthreads();
    // den[r] = (Q[r]·ksum_h)*f + N
    {
      int r = tid >> 3, seg = tid & 7;
      const float* kp = ksum + h * 128 + seg * 16;
      const float* qp = Qs + r * 132 + seg * 16;
      float p = 0.f;
#pragma unroll
      for (int c = 0; c < 16; ++c) p = fmaf(qp[c], kp[c], p);
      dred[r][seg] = p;
    }
    __syncthreads();
    if (tid < 32) {
      float t = 0.f;
#pragma unroll
      for (int s8 = 0; s8 < 8; ++s8) t += dred[tid][s8];
      den_s[tid] = t * fsh + 60000.0f;
    }
    // num-tile = Qs @ kvs[h]
    float acc[4][4];
#pragma unroll
    for (int i = 0; i < 4; ++i)
#pragma unroll
      for (int j = 0; j < 4; ++j) acc[i][j] = 0.f;
    for (int kk = 0; kk < 2; ++kk) {
      __syncthreads();
      for (int u = tid; u < 2048; u += 256) {
        int r = u >> 5, c = (u & 31) << 2;
        *reinterpret_cast<float4*>(&Ws[r * 128 + c]) =
            *reinterpret_cast<const float4*>(kvs + (size_t)h * 16384 +
                                             (size_t)(kk * 64 + r) * 128 + c);
      }
      __syncthreads();
#pragma unroll 4
      for (int k = 0; k < 64; k += 4) {
        float w[4][4];
#pragma unroll
        for (int dk = 0; dk < 4; ++dk)
          *reinterpret_cast<float4*>(w[dk]) =
              *reinterpret_cast<const float4*>(&Ws[(k + dk) * 128 + (ct << 2)]);
#pragma unroll
        for (int i = 0; i < 4; ++i) {
          float xv[4];
          *reinterpret_cast<float4*>(xv) =
              *reinterpret_cast<const float4*>(&Qs[(rt * 4 + i) * 132 + kk * 64 + k]);
#pragma unroll
          for (int dk = 0; dk < 4; ++dk)
#pragma unroll
            for (int j = 0; j < 4; ++j) acc[i][j] = fmaf(xv[dk], w[dk][j], acc[i][j]);
        }
      }
    }
    // apply epilogue for this head
    float f = fsh;
#pragma unroll
    for (int i = 0; i < 4; ++i) {
      int rg = row0 + rt * 4 + i;
      ushort4 v4 = *reinterpret_cast<const ushort4*>(
          Vb + (size_t)rg * 512 + h * 128 + (ct << 2));
      float rd = 1.0f / den_s[rt * 4 + i];
      out[i][0] += (acc[i][0] * f + 60000.0f * bf2f(v4.x)) * rd;
      out[i][1] += (acc[i][1] * f + 60000.0f * bf2f(v4.y)) * rd;
      out[i][2] += (acc[i][2] * f + 60000.0f * bf2f(v4.z)) * rd;
      out[i][3] += (acc[i][3] * f + 60000.0f * bf2f(v4.w)) * rd;
    }
  }
  // store attn (bf16), mean over heads
#pragma unroll
  for (int i = 0; i < 4; ++i) {
    int rg = row0 + rt * 4 + i;
    ushort4 s4;
    s4.x = f2bf(0.25f * out[i][0]); s4.y = f2bf(0.25f * out[i][1]);
    s4.z = f2bf(0.25f * out[i][2]); s4.w = f2bf(0.25f * out[i][3]);
    *reinterpret_cast<ushort4*>(attnb + (size_t)rg * 128 + (ct << 2)) = s4;
  }
}

// ---------------- host ----------------
extern "C" void kernel_launch(void* const* d_in, const int* in_sizes, int n_in,
                              void* d_out, int out_size, void* d_ws, size_t ws_size,
                              hipStream_t stream) {
  const float* x_ent = (const float*)d_in[0];
  const float* x_att = (const float*)d_in[1];
  const float* Wkqv_e = (const float*)d_in[2];
  const float* bkqv_e = (const float*)d_in[3];
  const float* Wkqv_a = (const float*)d_in[4];
  const float* bkqv_a = (const float*)d_in[5];
  const float* Wout_e = (const float*)d_in[6];
  const float* bout_e = (const float*)d_in[7];
  const float* Wout_a = (const float*)d_in[8];
  const float* bout_a = (const float*)d_in[9];
  const float* skip_e = (const float*)d_in[10];
  const float* skip_a = (const float*)d_in[11];
  const float* a_rel = (const float*)d_in[12];
  const float* m_rel = (const float*)d_in[13];
  const float* p_rel = (const float*)d_in[14];
  const float* ln_ent_g = (const float*)d_in[15];
  const float* ln_ent_b = (const float*)d_in[16];
  const float* sg_fc_W = (const float*)d_in[17];
  const float* sg_fc_b = (const float*)d_in[18];
  const float* sg_ln0_g = (const float*)d_in[19];
  const float* sg_ln0_b = (const float*)d_in[20];
  const float* sg_Wq = (const float*)d_in[21];
  const float* sg_bq = (const float*)d_in[22];
  const float* sg_Wk = (const float*)d_in[23];
  const float* sg_bk = (const float*)d_in[24];
  const float* sg_Wv = (const float*)d_in[25];
  const float* sg_bv = (const float*)d_in[26];
  const float* sg_ln1_g = (const float*)d_in[27];
  const float* sg_ln1_b = (const float*)d_in[28];
  const float* proj_W1 = (const float*)d_in[29];
  const float* proj_b1 = (const float*)d_in[30];
  const float* proj_W2 = (const float*)d_in[31];
  const float* proj_b2 = (const float*)d_in[32];
  const int* ei_ee = (const int*)d_in[33];
  const int* ei_ea = (const int*)d_in[34];
  const int* ei_ae = (const int*)d_in[35];

  char* ws = (char*)d_ws;
  // ---- workspace layout (bytes), total ~206.6 MB (ws_size >= 215.7 MB verified) ----
  const size_t O_HE = 0;                         // h_e f32 (30.72M)
  const size_t O_HA = 30720000;                  // h_a f32 (15.36M) | SG: attn_b bf16
  const size_t O_Z0 = 46080000;                  // z0 f32 (30.72M)
  const size_t O_WKT = 76800000;                 // 3*16384 f32
  const size_t O_WVT = 76996608;
  const size_t O_BKT = 77193216;
  const size_t O_BVT = 77194752;
  const size_t O_KVS = 77196288;                 // kvs(262144)+ksum(2048)+ssq(64)
  const size_t O_UN = 77460544;                  // union (129.12M)
  // HGT view of union:
  float* q_e = (float*)(ws + O_UN);
  float* q_a = (float*)(ws + O_UN + 30720000);
  float* Tbuf = (float*)(ws + O_UN + 46080000);
  float* outs_e = (float*)(ws + O_UN + 76800000);
  float* outs_a = (float*)(ws + O_UN + 107520000);
  float* logits = (float*)(ws + O_UN + 122880000);
  float* s_e = (float*)(ws + O_UN + 127680000);
  float* s_a = (float*)(ws + O_UN + 128640000);
  const size_t ZERO_OFF = O_UN + 76800000;
  const size_t ZERO_BYTES = 52320000;
  // SG view of union:
  float* tmpf = (float*)(ws + O_UN);                               // fc out (30.72M)
  unsigned short* Vb = (unsigned short*)(ws + O_UN);               // NE*512 bf16 (61.44M)
  unsigned short* KQb = (unsigned short*)(ws + O_UN + 61440000);   // K then Q (61.44M)
  unsigned short* attnb = (unsigned short*)(ws + O_HA);            // NE*128 bf16 (15.36M)

  float* h_e = (float*)(ws + O_HE);
  float* h_a = (float*)(ws + O_HA);
  float* z0 = (float*)(ws + O_Z0);
  float* Wkt = (float*)(ws + O_WKT);
  float* Wvt = (float*)(ws + O_WVT);
  float* bkt = (float*)(ws + O_BKT);
  float* bvt = (float*)(ws + O_BVT);
  float* kvs = (float*)(ws + O_KVS);
  float* ksum = (float*)(ws + O_KVS + 262144);
  float* ssq_q = (float*)(ws + O_KVS + 262144 + 2048);
  float* ssq_k = ssq_q + 1;

  const int GB_E = NE / 32;             // 1875 exact
  const int GB_A = (NA + 31) / 32;      // 938

  hipMemcpyAsync(h_e, x_ent, (size_t)NE * 128 * 4, hipMemcpyDeviceToDevice, stream);
  hipMemcpyAsync(h_a, x_att, (size_t)NA * 128 * 4, hipMemcpyDeviceToDevice, stream);

  const int* eis[3] = {ei_ee, ei_ea, ei_ae};
  const int Es[3] = {E_EE, E_EA, E_AE};
  const size_t offs[3] = {0, (size_t)E_EE * 4, (size_t)(E_EE + E_EA) * 4};
  float* hsrc[3]; int Nsrc[3]; int Gsrc[3]; float* qdst[3]; float* sdst[3]; float* odst[3];

  for (int l = 0; l < 2; ++l) {
    const float* Wke = Wkqv_e + (size_t)l * 49152;
    const float* Wka = Wkqv_a + (size_t)l * 49152;
    const float* bke = bkqv_e + (size_t)l * 384;
    const float* bka = bkqv_a + (size_t)l * 384;

    hsrc[0] = h_e; hsrc[1] = h_e; hsrc[2] = h_a;
    Nsrc[0] = NE; Nsrc[1] = NE; Nsrc[2] = NA;
    Gsrc[0] = GB_E; Gsrc[1] = GB_E; Gsrc[2] = GB_A;
    qdst[0] = q_e; qdst[1] = q_a; qdst[2] = q_e;
    sdst[0] = s_e; sdst[1] = s_a; sdst[2] = s_e;
    odst[0] = outs_e; odst[1] = outs_a; odst[2] = outs_e;

    wrel_k<<<dim3(3, 2), 256, 0, stream>>>(Wke, Wka, bke, bka,
                                           a_rel + (size_t)l * 12288,
                                           m_rel + (size_t)l * 12288, Wkt, Wvt, bkt, bvt);
    // q projections (cols 128..255 of Wkqv)
    gemm32_k<0, 0><<<GB_E, 256, 0, stream>>>(h_e, 128, Wke + 128, 384, bke + 128, NE,
                                             q_e, nullptr, 128, nullptr, nullptr);
    gemm32_k<0, 0><<<GB_A, 256, 0, stream>>>(h_a, 128, Wka + 128, 384, bka + 128, NA,
                                             q_a, nullptr, 128, nullptr, nullptr);
    hipMemsetAsync(ws + ZERO_OFF, 0, ZERO_BYTES, stream);

    // edge weights per relation (kt transient in Tbuf); exp + seg-sum fused
    for (int t = 0; t < 3; ++t) {
      gemm32_k<0, 0><<<Gsrc[t], 256, 0, stream>>>(hsrc[t], 128, Wkt + t * 16384, 128,
                                                  bkt + t * 128, Nsrc[t], Tbuf, nullptr,
                                                  128, nullptr, nullptr);
      edge_w_k<<<(Es[t] * 4 + 255) / 256, 256, 0, stream>>>(
          qdst[t], Tbuf, eis[t], Es[t], p_rel + (size_t)(l * 3 + t) * 4,
          logits + offs[t], sdst[t]);
    }
    for (int t = 0; t < 3; ++t) {
      gemm32_k<0, 0><<<Gsrc[t], 256, 0, stream>>>(hsrc[t], 128, Wvt + t * 16384, 128,
                                                  bvt + t * 128, Nsrc[t], Tbuf, nullptr,
                                                  128, nullptr, nullptr);
      aggregate_k<<<(Es[t] * 4 + 255) / 256, 256, 0, stream>>>(
          logits + offs[t], eis[t], Es[t], sdst[t], Tbuf, odst[t]);
    }
    // out proj (gelu on msg) + gated skip + inter-layer gelu, in-place on h
    gemm32_k<1, 3><<<GB_E, 256, 0, stream>>>(outs_e, 128, Wout_e + (size_t)l * 16384, 128,
                                             bout_e + (size_t)l * 128, NE, h_e, nullptr,
                                             128, skip_e + l, nullptr);
    gemm32_k<1, 3><<<GB_A, 256, 0, stream>>>(outs_a, 128, Wout_a + (size_t)l * 16384, 128,
                                             bout_a + (size_t)l * 128, NA, h_a, nullptr,
                                             128, skip_a + l, nullptr);
  }

  // -------- SGFormer --------
  gemm32_k<0, 0><<<GB_E, 256, 0, stream>>>(h_e, 128, sg_fc_W, 128, sg_fc_b, NE,
                                           tmpf, nullptr, 128, nullptr, nullptr);
  ln_k<float, float><<<NE, 128, 0, stream>>>(tmpf, nullptr, 1.f, 0.f, sg_ln0_g,
                                             sg_ln0_b, z0, 1);
  hipMemsetAsync(ws + O_KVS, 0, 264256, stream);
  // V, K (bf16, K with ssq_k) -- 4 col-blocks each via gridDim.y
  gemm32_k<0, 2><<<dim3(GB_E, 4), 256, 0, stream>>>(z0, 128, sg_Wv, 512, sg_bv, NE,
                                                    nullptr, Vb, 512, nullptr, nullptr);
  gemm32_k<0, 2><<<dim3(GB_E, 4), 256, 0, stream>>>(z0, 128, sg_Wk, 512, sg_bk, NE,
                                                    nullptr, KQb, 512, nullptr, ssq_k);
  kvsred_k<<<dim3(64, 4), 256, 0, stream>>>(KQb, Vb, kvs, ksum, NE, 938);
  // Q overwrites K region (+ ssq_q)
  gemm32_k<0, 2><<<dim3(GB_E, 4), 256, 0, stream>>>(z0, 128, sg_Wq, 512, sg_bq, NE,
                                                    nullptr, KQb, 512, nullptr, ssq_q);
  sgapply_k<<<GB_E, 256, 0, stream>>>(KQb, Vb, kvs, ksum, ssq_q, ssq_k, attnb);
  // h_global = LN(0.5*attn + 0.5*z0) -> z0 (in-place over B)
  ln_k<unsigned short, float><<<NE, 128, 0, stream>>>(attnb, z0, 0.5f, 0.5f, sg_ln1_g,
                                                      sg_ln1_b, z0, 0);
  // h_ent = LN(0.9*h_e + 0.1*h_global) -> h_e (in-place over A)
  ln_k<float, float><<<NE, 128, 0, stream>>>(h_e, z0, 0.9f, 0.1f, ln_ent_g, ln_ent_b,
                                             h_e, 0);
  // projector MLP
  gemm32_k<0, 1><<<GB_E, 256, 0, stream>>>(h_e, 128, proj_W1, 128, proj_b1, NE,
                                           z0, nullptr, 128, nullptr, nullptr);
  gemm32_k<0, 0><<<GB_E, 256, 0, stream>>>(z0, 128, proj_W2, 128, proj_b2, NE,
                                           (float*)d_out, nullptr, 128, nullptr, nullptr);
}

// Round 8
// 2793.610 us; speedup vs baseline: 3.8644x; 2.4431x over previous
//
#include <hip/hip_runtime.h>

// ---------------- constants ----------------
#define NE 60000
#define NA 30000
#define E_EE 150000
#define E_EA 75000
#define E_AE 75000
#define SCALE 0.17677669529663689f   // 1/sqrt(32)

__device__ __forceinline__ float bf2f(unsigned short u) {
  return __uint_as_float(((unsigned)u) << 16);
}
__device__ __forceinline__ unsigned short f2bf(float f) {
  unsigned u = __float_as_uint(f);
  u = u + 0x7FFFu + ((u >> 16) & 1u);   // RNE
  return (unsigned short)(u >> 16);
}
__device__ __forceinline__ float ldc(const float* p) { return *p; }
__device__ __forceinline__ float ldc(const unsigned short* p) { return bf2f(*p); }
__device__ __forceinline__ float gelu_f(float x) {
  return 0.5f * x * (1.0f + erff(x * 0.7071067811865476f));
}

// ---------------- fused relation weights (all f32) ----------------
__global__ __launch_bounds__(256) void wrel_k(
    const float* __restrict__ Wk_e, const float* __restrict__ Wk_a,
    const float* __restrict__ bk_e, const float* __restrict__ bk_a,
    const float* __restrict__ a_rel, const float* __restrict__ m_rel,
    float* __restrict__ Wkt, float* __restrict__ Wvt,
    float* __restrict__ bkt, float* __restrict__ bvt) {
  int t = blockIdx.x;        // relation 0..2
  int part = blockIdx.y;     // 0: key (a_rel, cols 0..127), 1: value (m_rel, cols 256..)
  const float* W = (t < 2) ? Wk_e : Wk_a;
  const float* bb = (t < 2) ? bk_e : bk_a;
  const float* A = (part ? m_rel : a_rel) + t * 4096;
  int coff = part ? 256 : 0;
  float* Wo = (part ? Wvt : Wkt) + t * 16384;
  float* bo = (part ? bvt : bkt) + t * 128;
  __shared__ float As[4096];
  for (int u = threadIdx.x; u < 4096; u += 256) As[u] = A[u];
  __syncthreads();
  for (int u = threadIdx.x; u < 16384; u += 256) {
    int i = u >> 7, c = u & 127;
    int hh = c >> 5, e = c & 31;
    const float* wr = W + i * 384 + coff + hh * 32;
    const float* ar = As + hh * 1024 + e;
    float acc = 0.f;
#pragma unroll
    for (int d = 0; d < 32; ++d) acc = fmaf(wr[d], ar[d * 32], acc);
    Wo[u] = acc;
  }
  if (threadIdx.x < 128) {
    int c = threadIdx.x, hh = c >> 5, e = c & 31;
    const float* br = bb + coff + hh * 32;
    const float* ar = As + hh * 1024 + e;
    float acc = 0.f;
#pragma unroll
    for (int d = 0; d < 32; ++d) acc = fmaf(br[d], ar[d * 32], acc);
    bo[c] = acc;
  }
}

// ---------------- tiled GEMM: 32 rows x 128 cols per block, 256 threads -------------
// ACT: 0 none, 1 gelu(X).
// EPI: 0 f32 store; 1 relu f32; 2 bf16 store (+ atomic ssq if ssq!=null);
//      3 blend: fout = gelu(g*acc + (1-g)*fout), g = sigmoid(*skipp)
template <int ACT, int EPI>
__global__ __launch_bounds__(256) void gemm32_k(
    const float* __restrict__ X, int ldx,
    const float* __restrict__ W, int ldw,
    const float* __restrict__ bias, int N,
    float* __restrict__ fout, unsigned short* __restrict__ bout, int ldo,
    const float* __restrict__ skipp, float* __restrict__ ssq) {
  __shared__ float Ws[64 * 128];
  __shared__ float Xs[32 * 132];
  const int tid = threadIdx.x;
  const int ct = tid & 31, rt = tid >> 5;
  const int row0 = blockIdx.x * 32;
  const int cb = blockIdx.y * 128;

  for (int u = tid; u < 1024; u += 256) {
    int r = u >> 5, c = (u & 31) << 2;
    int rg = row0 + r;
    if (rg >= N) rg = N - 1;
    float4 v = *reinterpret_cast<const float4*>(X + (size_t)rg * ldx + c);
    if (ACT == 1) {
      v.x = gelu_f(v.x); v.y = gelu_f(v.y); v.z = gelu_f(v.z); v.w = gelu_f(v.w);
    }
    *reinterpret_cast<float4*>(&Xs[r * 132 + c]) = v;
  }

  float acc[4][4];
  {
    float bc[4] = {0.f, 0.f, 0.f, 0.f};
    if (bias) {
#pragma unroll
      for (int j = 0; j < 4; ++j) bc[j] = bias[cb + (ct << 2) + j];
    }
#pragma unroll
    for (int i = 0; i < 4; ++i)
#pragma unroll
      for (int j = 0; j < 4; ++j) acc[i][j] = bc[j];
  }

  for (int kk = 0; kk < 2; ++kk) {
    __syncthreads();
    for (int u = tid; u < 2048; u += 256) {
      int r = u >> 5, c = (u & 31) << 2;
      *reinterpret_cast<float4*>(&Ws[r * 128 + c]) =
          *reinterpret_cast<const float4*>(W + (size_t)(kk * 64 + r) * ldw + cb + c);
    }
    __syncthreads();
#pragma unroll 4
    for (int k = 0; k < 64; k += 4) {
      float w[4][4];
#pragma unroll
      for (int dk = 0; dk < 4; ++dk)
        *reinterpret_cast<float4*>(w[dk]) =
            *reinterpret_cast<const float4*>(&Ws[(k + dk) * 128 + (ct << 2)]);
#pragma unroll
      for (int i = 0; i < 4; ++i) {
        float xv[4];
        *reinterpret_cast<float4*>(xv) =
            *reinterpret_cast<const float4*>(&Xs[(rt * 4 + i) * 132 + kk * 64 + k]);
#pragma unroll
        for (int dk = 0; dk < 4; ++dk)
#pragma unroll
          for (int j = 0; j < 4; ++j) acc[i][j] = fmaf(xv[dk], w[dk][j], acc[i][j]);
      }
    }
  }

  const int colb = cb + (ct << 2);
  if (EPI == 0 || EPI == 1) {
#pragma unroll
    for (int i = 0; i < 4; ++i) {
      int rg = row0 + rt * 4 + i;
      if (rg < N) {
        float4 v = make_float4(acc[i][0], acc[i][1], acc[i][2], acc[i][3]);
        if (EPI == 1) {
          v.x = fmaxf(v.x, 0.f); v.y = fmaxf(v.y, 0.f);
          v.z = fmaxf(v.z, 0.f); v.w = fmaxf(v.w, 0.f);
        }
        *reinterpret_cast<float4*>(fout + (size_t)rg * ldo + colb) = v;
      }
    }
  } else if (EPI == 2) {
    float loc = 0.f;
#pragma unroll
    for (int i = 0; i < 4; ++i) {
      int rg = row0 + rt * 4 + i;
      if (rg < N) {
        ushort4 s;
        s.x = f2bf(acc[i][0]); s.y = f2bf(acc[i][1]);
        s.z = f2bf(acc[i][2]); s.w = f2bf(acc[i][3]);
        *reinterpret_cast<ushort4*>(bout + (size_t)rg * ldo + colb) = s;
        loc += acc[i][0] * acc[i][0] + acc[i][1] * acc[i][1] +
               acc[i][2] * acc[i][2] + acc[i][3] * acc[i][3];
      }
    }
    if (ssq) {
      __syncthreads();
      Xs[tid] = loc;
      __syncthreads();
      if (tid < 128) Xs[tid] += Xs[tid + 128];
      __syncthreads();
      if (tid < 64) {
        float v = Xs[tid] + Xs[tid + 64];
#pragma unroll
        for (int m = 32; m > 0; m >>= 1) v += __shfl_down(v, m, 64);
        if (tid == 0) atomicAdd(ssq, v);
      }
    }
  } else {  // EPI == 3
    float g = 1.f / (1.f + expf(-*skipp));
    float g1 = 1.f - g;
#pragma unroll
    for (int i = 0; i < 4; ++i) {
      int rg = row0 + rt * 4 + i;
      if (rg < N) {
        float4 old = *reinterpret_cast<const float4*>(fout + (size_t)rg * ldo + colb);
        float4 v;
        v.x = gelu_f(g * acc[i][0] + g1 * old.x);
        v.y = gelu_f(g * acc[i][1] + g1 * old.y);
        v.z = gelu_f(g * acc[i][2] + g1 * old.z);
        v.w = gelu_f(g * acc[i][3] + g1 * old.w);
        *reinterpret_cast<float4*>(fout + (size_t)rg * ldo + colb) = v;
      }
    }
  }
}

// ---------------- CSR build ----------------
__global__ __launch_bounds__(256) void deg_k(const int* __restrict__ ei, int E,
                                             int* __restrict__ deg) {
  int i = blockIdx.x * 256 + threadIdx.x;
  if (i < E) atomicAdd(&deg[ei[E + i]], 1);
}

// exclusive scan over deg_cursor[0..n), writing rowptr[0..n] and exclusive back
// into deg_cursor (becomes the fill cursor). Single block, 1024 threads.
__global__ __launch_bounds__(1024) void scan_k(int* __restrict__ deg_cursor,
                                               int* __restrict__ rowptr, int n) {
  __shared__ int sd[1024];
  __shared__ int carry;
  int tid = threadIdx.x;
  if (tid == 0) carry = 0;
  __syncthreads();
  for (int base = 0; base < n; base += 1024) {
    int v = (base + tid < n) ? deg_cursor[base + tid] : 0;
    sd[tid] = v;
    __syncthreads();
    for (int off = 1; off < 1024; off <<= 1) {
      int t = (tid >= off) ? sd[tid - off] : 0;
      __syncthreads();
      sd[tid] += t;
      __syncthreads();
    }
    int c0 = carry;
    if (base + tid < n) {
      int excl = c0 + sd[tid] - v;
      rowptr[base + tid] = excl;
      deg_cursor[base + tid] = excl;
    }
    __syncthreads();
    if (tid == 0) carry = c0 + sd[1023];
    __syncthreads();
  }
  if (tid == 0) rowptr[n] = carry;
}

__global__ __launch_bounds__(256) void fill_k(const int* __restrict__ ei, int E,
                                              int* __restrict__ cursor,
                                              int* __restrict__ entries,
                                              int srcoff, int tag) {
  int i = blockIdx.x * 256 + threadIdx.x;
  if (i < E) {
    int pos = atomicAdd(&cursor[ei[E + i]], 1);
    entries[pos] = (ei[i] + srcoff) | (tag << 30);
  }
}

// ---------------- HGT gather: one 32-lane group per (dst, head), no atomics --------
// out[dst, h*32+c] = sum_e w_e * vt[lin_e, h*32+c] / (sum_e w_e + 1e-16)
// w_e = exp( dot32(q[dst,h,:], kt[lin_e,h,:]) * SCALE * pbase[tag*8 + h] )
// out may alias q (each group reads only its own (dst,h) q-columns before writing).
__global__ __launch_bounds__(256) void hgt_gather_k(
    const float* __restrict__ q, const unsigned short* __restrict__ ktbl,
    const unsigned short* __restrict__ vtbl, const int* __restrict__ rowptr,
    const int* __restrict__ entries, const float* __restrict__ pbase, int nd,
    float* __restrict__ out) {
  int g = blockIdx.x * 8 + (threadIdx.x >> 5);
  int dst = g >> 2, h = g & 3, c = threadIdx.x & 31;
  if (dst >= nd) return;
  int col = h * 32 + c;
  float qv = q[(size_t)dst * 128 + col];
  int i0 = rowptr[dst], i1 = rowptr[dst + 1];
  float sum = 0.f, acc = 0.f;
  for (int i = i0; i < i1; ++i) {
    int e = entries[i];
    int lin = e & 0x3FFFFFFF;
    int tag = (unsigned)e >> 30;
    float part = qv * bf2f(ktbl[(size_t)lin * 128 + col]);
#pragma unroll
    for (int m = 16; m > 0; m >>= 1) part += __shfl_xor(part, m);
    float w = expf(part * SCALE * pbase[tag * 8 + h]);
    sum += w;
    acc = fmaf(w, bf2f(vtbl[(size_t)lin * 128 + col]), acc);
  }
  out[(size_t)dst * 128 + col] = acc / (sum + 1e-16f);
}

// ---------------- LayerNorm (row=128): out = LN(alpha*A + beta*B)*g + b -------------
template <typename AT, typename BT>
__global__ __launch_bounds__(128) void ln_k(const AT* __restrict__ A,
                                            const BT* __restrict__ B, float alpha,
                                            float beta, const float* __restrict__ g,
                                            const float* __restrict__ b,
                                            float* __restrict__ out, int relu) {
  int row = blockIdx.x;
  int t = threadIdx.x;
  float v = alpha * ldc(A + (size_t)row * 128 + t);
  if (B) v += beta * ldc(B + (size_t)row * 128 + t);
  float s1 = v, s2 = v * v;
#pragma unroll
  for (int m = 32; m > 0; m >>= 1) {
    s1 += __shfl_xor(s1, m, 64);
    s2 += __shfl_xor(s2, m, 64);
  }
  __shared__ float r1[2], r2[2];
  int w = t >> 6;
  if ((t & 63) == 0) { r1[w] = s1; r2[w] = s2; }
  __syncthreads();
  float S1 = r1[0] + r1[1], S2 = r2[0] + r2[1];
  float mu = S1 * (1.f / 128.f);
  float var = S2 * (1.f / 128.f) - mu * mu;
  float rr = rsqrtf(fmaxf(var, 0.f) + 1e-5f);
  float o = (v - mu) * rr * g[t] + b[t];
  if (relu) o = fmaxf(o, 0.f);
  out[(size_t)row * 128 + t] = o;
}

// ---------------- kvs[h][m][d] = sum_n K[n,h,m]*V[n,h,d]; ksum[h][m] ----------------
__global__ __launch_bounds__(256) void kvsred_k(const unsigned short* __restrict__ Kb,
                                                const unsigned short* __restrict__ Vb,
                                                float* __restrict__ kvs,
                                                float* __restrict__ ksum, int N, int chunk) {
  int h = blockIdx.y;
  int n0 = blockIdx.x * chunk;
  int n1 = n0 + chunk; if (n1 > N) n1 = N;
  __shared__ float ks[8][132];
  __shared__ float vs[8][132];
  float acc[8][8];
#pragma unroll
  for (int i = 0; i < 8; ++i)
#pragma unroll
    for (int j = 0; j < 8; ++j) acc[i][j] = 0.f;
  float ksloc = 0.f;
  int ti = threadIdx.x >> 4, tj = threadIdx.x & 15;
  for (int n = n0; n < n1; n += 8) {
    __syncthreads();
    for (int u = threadIdx.x; u < 2048; u += 256) {
      int which = u >> 10;
      int ni = (u >> 7) & 7, c = u & 127;
      int ng = n + ni;
      float val = 0.f;
      if (ng < n1)
        val = bf2f((which ? Vb : Kb)[(size_t)ng * 512 + h * 128 + c]);
      (which ? vs : ks)[ni][c] = val;
    }
    __syncthreads();
#pragma unroll
    for (int ni = 0; ni < 8; ++ni) {
      float kk[8], vv[8];
#pragma unroll
      for (int u = 0; u < 8; ++u) { kk[u] = ks[ni][ti * 8 + u]; vv[u] = vs[ni][tj * 8 + u]; }
#pragma unroll
      for (int i = 0; i < 8; ++i)
#pragma unroll
        for (int j = 0; j < 8; ++j) acc[i][j] = fmaf(kk[i], vv[j], acc[i][j]);
      if (threadIdx.x < 128) ksloc += ks[ni][threadIdx.x];
    }
  }
#pragma unroll
  for (int i = 0; i < 8; ++i)
#pragma unroll
    for (int j = 0; j < 8; ++j)
      atomicAdd(&kvs[((size_t)h * 128 + ti * 8 + i) * 128 + tj * 8 + j], acc[i][j]);
  if (threadIdx.x < 128) atomicAdd(&ksum[h * 128 + threadIdx.x], ksloc);
}

// ---------------- SG attention apply: 32-row tile, kvs[h] in LDS, den fused ---------
__global__ __launch_bounds__(256) void sgapply_k(const unsigned short* __restrict__ Qb,
                                                 const unsigned short* __restrict__ Vb,
                                                 const float* __restrict__ kvs,
                                                 const float* __restrict__ ksum,
                                                 const float* __restrict__ ssqq,
                                                 const float* __restrict__ ssqk,
                                                 unsigned short* __restrict__ attnb) {
  __shared__ float Qs[32 * 132];
  __shared__ float Ws[64 * 128];
  __shared__ float dred[32][9];
  __shared__ float den_s[32];
  __shared__ float fsh;
  const int tid = threadIdx.x;
  const int ct = tid & 31, rt = tid >> 5;
  const int row0 = blockIdx.x * 32;
  if (tid == 0) fsh = 1.0f / (sqrtf(*ssqq) * sqrtf(*ssqk));
  float out[4][4];
#pragma unroll
  for (int i = 0; i < 4; ++i)
#pragma unroll
    for (int j = 0; j < 4; ++j) out[i][j] = 0.f;

  for (int h = 0; h < 4; ++h) {
    __syncthreads();
    for (int u = tid; u < 1024; u += 256) {
      int r = u >> 5, c = (u & 31) << 2;
      ushort4 q4 = *reinterpret_cast<const ushort4*>(
          Qb + (size_t)(row0 + r) * 512 + h * 128 + c);
      float4 v = make_float4(bf2f(q4.x), bf2f(q4.y), bf2f(q4.z), bf2f(q4.w));
      *reinterpret_cast<float4*>(&Qs[r * 132 + c]) = v;
    }
    __syncthreads();
    {
      int r = tid >> 3, seg = tid & 7;
      const float* kp = ksum + h * 128 + seg * 16;
      const float* qp = Qs + r * 132 + seg * 16;
      float p = 0.f;
#pragma unroll
      for (int c = 0; c < 16; ++c) p = fmaf(qp[c], kp[c], p);
      dred[r][seg] = p;
    }
    __syncthreads();
    if (tid < 32) {
      float t = 0.f;
#pragma unroll
      for (int s8 = 0; s8 < 8; ++s8) t += dred[tid][s8];
      den_s[tid] = t * fsh + 60000.0f;
    }
    float acc[4][4];
#pragma unroll
    for (int i = 0; i < 4; ++i)
#pragma unroll
      for (int j = 0; j < 4; ++j) acc[i][j] = 0.f;
    for (int kk = 0; kk < 2; ++kk) {
      __syncthreads();
      for (int u = tid; u < 2048; u += 256) {
        int r = u >> 5, c = (u & 31) << 2;
        *reinterpret_cast<float4*>(&Ws[r * 128 + c]) =
            *reinterpret_cast<const float4*>(kvs + (size_t)h * 16384 +
                                             (size_t)(kk * 64 + r) * 128 + c);
      }
      __syncthreads();
#pragma unroll 4
      for (int k = 0; k < 64; k += 4) {
        float w[4][4];
#pragma unroll
        for (int dk = 0; dk < 4; ++dk)
          *reinterpret_cast<float4*>(w[dk]) =
              *reinterpret_cast<const float4*>(&Ws[(k + dk) * 128 + (ct << 2)]);
#pragma unroll
        for (int i = 0; i < 4; ++i) {
          float xv[4];
          *reinterpret_cast<float4*>(xv) =
              *reinterpret_cast<const float4*>(&Qs[(rt * 4 + i) * 132 + kk * 64 + k]);
#pragma unroll
          for (int dk = 0; dk < 4; ++dk)
#pragma unroll
            for (int j = 0; j < 4; ++j) acc[i][j] = fmaf(xv[dk], w[dk][j], acc[i][j]);
        }
      }
    }
    float f = fsh;
#pragma unroll
    for (int i = 0; i < 4; ++i) {
      int rg = row0 + rt * 4 + i;
      ushort4 v4 = *reinterpret_cast<const ushort4*>(
          Vb + (size_t)rg * 512 + h * 128 + (ct << 2));
      float rd = 1.0f / den_s[rt * 4 + i];
      out[i][0] += (acc[i][0] * f + 60000.0f * bf2f(v4.x)) * rd;
      out[i][1] += (acc[i][1] * f + 60000.0f * bf2f(v4.y)) * rd;
      out[i][2] += (acc[i][2] * f + 60000.0f * bf2f(v4.z)) * rd;
      out[i][3] += (acc[i][3] * f + 60000.0f * bf2f(v4.w)) * rd;
    }
  }
#pragma unroll
  for (int i = 0; i < 4; ++i) {
    int rg = row0 + rt * 4 + i;
    ushort4 s4;
    s4.x = f2bf(0.25f * out[i][0]); s4.y = f2bf(0.25f * out[i][1]);
    s4.z = f2bf(0.25f * out[i][2]); s4.w = f2bf(0.25f * out[i][3]);
    *reinterpret_cast<ushort4*>(attnb + (size_t)rg * 128 + (ct << 2)) = s4;
  }
}

// ---------------- host ----------------
extern "C" void kernel_launch(void* const* d_in, const int* in_sizes, int n_in,
                              void* d_out, int out_size, void* d_ws, size_t ws_size,
                              hipStream_t stream) {
  const float* x_ent = (const float*)d_in[0];
  const float* x_att = (const float*)d_in[1];
  const float* Wkqv_e = (const float*)d_in[2];
  const float* bkqv_e = (const float*)d_in[3];
  const float* Wkqv_a = (const float*)d_in[4];
  const float* bkqv_a = (const float*)d_in[5];
  const float* Wout_e = (const float*)d_in[6];
  const float* bout_e = (const float*)d_in[7];
  const float* Wout_a = (const float*)d_in[8];
  const float* bout_a = (const float*)d_in[9];
  const float* skip_e = (const float*)d_in[10];
  const float* skip_a = (const float*)d_in[11];
  const float* a_rel = (const float*)d_in[12];
  const float* m_rel = (const float*)d_in[13];
  const float* p_rel = (const float*)d_in[14];
  const float* ln_ent_g = (const float*)d_in[15];
  const float* ln_ent_b = (const float*)d_in[16];
  const float* sg_fc_W = (const float*)d_in[17];
  const float* sg_fc_b = (const float*)d_in[18];
  const float* sg_ln0_g = (const float*)d_in[19];
  const float* sg_ln0_b = (const float*)d_in[20];
  const float* sg_Wq = (const float*)d_in[21];
  const float* sg_bq = (const float*)d_in[22];
  const float* sg_Wk = (const float*)d_in[23];
  const float* sg_bk = (const float*)d_in[24];
  const float* sg_Wv = (const float*)d_in[25];
  const float* sg_bv = (const float*)d_in[26];
  const float* sg_ln1_g = (const float*)d_in[27];
  const float* sg_ln1_b = (const float*)d_in[28];
  const float* proj_W1 = (const float*)d_in[29];
  const float* proj_b1 = (const float*)d_in[30];
  const float* proj_W2 = (const float*)d_in[31];
  const float* proj_b2 = (const float*)d_in[32];
  const int* ei_ee = (const int*)d_in[33];
  const int* ei_ea = (const int*)d_in[34];
  const int* ei_ae = (const int*)d_in[35];

  char* ws = (char*)d_ws;
  // ---- fixed region ----
  const size_t O_HE = 0;                         // h_e f32 (30.72M)
  const size_t O_HA = 30720000;                  // h_a f32 (15.36M) | SG: attnb bf16
  const size_t O_Z0 = 46080000;                  // z0 f32 (30.72M)
  const size_t O_WKT = 76800000;                 // 3*16384 f32
  const size_t O_WVT = 76996608;
  const size_t O_BKT = 77193216;
  const size_t O_BVT = 77194752;
  const size_t O_KVS = 77196288;                 // kvs(262144)+ksum(2048)+ssq(64)
  // ---- CSR region ----
  const size_t O_RPE = 77460544;                 // rowptr_e (60001) -> 240064
  const size_t O_RPA = O_RPE + 240064;           // rowptr_a (30001) -> 120064
  const size_t O_CUE = O_RPA + 120064;           // cursor/deg_e -> 240000
  const size_t O_CUA = O_CUE + 240000;           // cursor/deg_a -> 120000
  const size_t O_ENE = O_CUA + 120000;           // entries_e (225000) -> 900000
  const size_t O_ENA = O_ENE + 900000;           // entries_a (75000) -> 300000
  const size_t O_UN = O_ENA + 300000;            // union; 79,380,672
  // HGT view of union:
  float* q_e = (float*)(ws + O_UN);                                 // 30.72M (also out_e)
  float* q_a = (float*)(ws + O_UN + 30720000);                      // 15.36M (also out_a)
  unsigned short* ktbl = (unsigned short*)(ws + O_UN + 46080000);   // 150000x128 bf16
  unsigned short* vtbl = (unsigned short*)(ws + O_UN + 84480000);   // 150000x128 bf16
  // SG view of union:
  float* tmpf = (float*)(ws + O_UN);                                // fc out f32
  unsigned short* Vb = (unsigned short*)(ws + O_UN);                // NE*512 bf16
  unsigned short* KQb = (unsigned short*)(ws + O_UN + 61440000);    // K then Q
  unsigned short* attnb = (unsigned short*)(ws + O_HA);             // NE*128 bf16

  float* h_e = (float*)(ws + O_HE);
  float* h_a = (float*)(ws + O_HA);
  float* z0 = (float*)(ws + O_Z0);
  float* Wkt = (float*)(ws + O_WKT);
  float* Wvt = (float*)(ws + O_WVT);
  float* bkt = (float*)(ws + O_BKT);
  float* bvt = (float*)(ws + O_BVT);
  float* kvs = (float*)(ws + O_KVS);
  float* ksum = (float*)(ws + O_KVS + 262144);
  float* ssq_q = (float*)(ws + O_KVS + 262144 + 2048);
  float* ssq_k = ssq_q + 1;
  int* rowptr_e = (int*)(ws + O_RPE);
  int* rowptr_a = (int*)(ws + O_RPA);
  int* cursor_e = (int*)(ws + O_CUE);
  int* cursor_a = (int*)(ws + O_CUA);
  int* entries_e = (int*)(ws + O_ENE);
  int* entries_a = (int*)(ws + O_ENA);

  const int GB_E = NE / 32;             // 1875 exact
  const int GB_A = (NA + 31) / 32;      // 938

  hipMemcpyAsync(h_e, x_ent, (size_t)NE * 128 * 4, hipMemcpyDeviceToDevice, stream);
  hipMemcpyAsync(h_a, x_att, (size_t)NA * 128 * 4, hipMemcpyDeviceToDevice, stream);

  // ---- CSR build (graph identical across layers) ----
  hipMemsetAsync(ws + O_CUE, 0, 360000, stream);   // cursor_e + cursor_a
  deg_k<<<(E_EE + 255) / 256, 256, 0, stream>>>(ei_ee, E_EE, cursor_e);
  deg_k<<<(E_AE + 255) / 256, 256, 0, stream>>>(ei_ae, E_AE, cursor_e);
  deg_k<<<(E_EA + 255) / 256, 256, 0, stream>>>(ei_ea, E_EA, cursor_a);
  scan_k<<<1, 1024, 0, stream>>>(cursor_e, rowptr_e, NE);
  scan_k<<<1, 1024, 0, stream>>>(cursor_a, rowptr_a, NA);
  fill_k<<<(E_EE + 255) / 256, 256, 0, stream>>>(ei_ee, E_EE, cursor_e, entries_e, 0, 0);
  fill_k<<<(E_AE + 255) / 256, 256, 0, stream>>>(ei_ae, E_AE, cursor_e, entries_e, NE, 1);
  fill_k<<<(E_EA + 255) / 256, 256, 0, stream>>>(ei_ea, E_EA, cursor_a, entries_a, 0, 0);

  for (int l = 0; l < 2; ++l) {
    const float* Wke = Wkqv_e + (size_t)l * 49152;
    const float* Wka = Wkqv_a + (size_t)l * 49152;
    const float* bke = bkqv_e + (size_t)l * 384;
    const float* bka = bkqv_a + (size_t)l * 384;

    wrel_k<<<dim3(3, 2), 256, 0, stream>>>(Wke, Wka, bke, bka,
                                           a_rel + (size_t)l * 12288,
                                           m_rel + (size_t)l * 12288, Wkt, Wvt, bkt, bvt);
    // q projections (cols 128..255 of Wkqv)
    gemm32_k<0, 0><<<GB_E, 256, 0, stream>>>(h_e, 128, Wke + 128, 384, bke + 128, NE,
                                             q_e, nullptr, 128, nullptr, nullptr);
    gemm32_k<0, 0><<<GB_A, 256, 0, stream>>>(h_a, 128, Wka + 128, 384, bka + 128, NA,
                                             q_a, nullptr, 128, nullptr, nullptr);
    // kt/vt tables (bf16): rows [0,NE)=rel0(src e), [NE,NE+NA)=rel2(src a),
    //                      [90000,150000)=rel1(src e, dst a)
    gemm32_k<0, 2><<<GB_E, 256, 0, stream>>>(h_e, 128, Wkt, 128, bkt, NE,
                                             nullptr, ktbl, 128, nullptr, nullptr);
    gemm32_k<0, 2><<<GB_A, 256, 0, stream>>>(h_a, 128, Wkt + 2 * 16384, 128,
                                             bkt + 2 * 128, NA, nullptr,
                                             ktbl + (size_t)NE * 128, 128, nullptr, nullptr);
    gemm32_k<0, 2><<<GB_E, 256, 0, stream>>>(h_e, 128, Wkt + 1 * 16384, 128,
                                             bkt + 1 * 128, NE, nullptr,
                                             ktbl + (size_t)90000 * 128, 128, nullptr, nullptr);
    gemm32_k<0, 2><<<GB_E, 256, 0, stream>>>(h_e, 128, Wvt, 128, bvt, NE,
                                             nullptr, vtbl, 128, nullptr, nullptr);
    gemm32_k<0, 2><<<GB_A, 256, 0, stream>>>(h_a, 128, Wvt + 2 * 16384, 128,
                                             bvt + 2 * 128, NA, nullptr,
                                             vtbl + (size_t)NE * 128, 128, nullptr, nullptr);
    gemm32_k<0, 2><<<GB_E, 256, 0, stream>>>(h_e, 128, Wvt + 1 * 16384, 128,
                                             bvt + 1 * 128, NE, nullptr,
                                             vtbl + (size_t)90000 * 128, 128, nullptr, nullptr);
    // gather (writes message in-place over q buffers)
    hgt_gather_k<<<30000, 256, 0, stream>>>(q_e, ktbl, vtbl, rowptr_e, entries_e,
                                            p_rel + (size_t)l * 12, NE, q_e);
    hgt_gather_k<<<15000, 256, 0, stream>>>(q_a, ktbl + (size_t)90000 * 128,
                                            vtbl + (size_t)90000 * 128, rowptr_a,
                                            entries_a, p_rel + (size_t)l * 12 + 4, NA, q_a);
    // out proj (gelu on msg) + gated skip + inter-layer gelu, in-place on h
    gemm32_k<1, 3><<<GB_E, 256, 0, stream>>>(q_e, 128, Wout_e + (size_t)l * 16384, 128,
                                             bout_e + (size_t)l * 128, NE, h_e, nullptr,
                                             128, skip_e + l, nullptr);
    gemm32_k<1, 3><<<GB_A, 256, 0, stream>>>(q_a, 128, Wout_a + (size_t)l * 16384, 128,
                                             bout_a + (size_t)l * 128, NA, h_a, nullptr,
                                             128, skip_a + l, nullptr);
  }

  // -------- SGFormer --------
  gemm32_k<0, 0><<<GB_E, 256, 0, stream>>>(h_e, 128, sg_fc_W, 128, sg_fc_b, NE,
                                           tmpf, nullptr, 128, nullptr, nullptr);
  ln_k<float, float><<<NE, 128, 0, stream>>>(tmpf, nullptr, 1.f, 0.f, sg_ln0_g,
                                             sg_ln0_b, z0, 1);
  hipMemsetAsync(ws + O_KVS, 0, 264256, stream);
  gemm32_k<0, 2><<<dim3(GB_E, 4), 256, 0, stream>>>(z0, 128, sg_Wv, 512, sg_bv, NE,
                                                    nullptr, Vb, 512, nullptr, nullptr);
  gemm32_k<0, 2><<<dim3(GB_E, 4), 256, 0, stream>>>(z0, 128, sg_Wk, 512, sg_bk, NE,
                                                    nullptr, KQb, 512, nullptr, ssq_k);
  kvsred_k<<<dim3(64, 4), 256, 0, stream>>>(KQb, Vb, kvs, ksum, NE, 938);
  gemm32_k<0, 2><<<dim3(GB_E, 4), 256, 0, stream>>>(z0, 128, sg_Wq, 512, sg_bq, NE,
                                                    nullptr, KQb, 512, nullptr, ssq_q);
  sgapply_k<<<GB_E, 256, 0, stream>>>(KQb, Vb, kvs, ksum, ssq_q, ssq_k, attnb);
  ln_k<unsigned short, float><<<NE, 128, 0, stream>>>(attnb, z0, 0.5f, 0.5f, sg_ln1_g,
                                                      sg_ln1_b, z0, 0);
  ln_k<float, float><<<NE, 128, 0, stream>>>(h_e, z0, 0.9f, 0.1f, ln_ent_g, ln_ent_b,
                                             h_e, 0);
  gemm32_k<0, 1><<<GB_E, 256, 0, stream>>>(h_e, 128, proj_W1, 128, proj_b1, NE,
                                           z0, nullptr, 128, nullptr, nullptr);
  gemm32_k<0, 0><<<GB_E, 256, 0, stream>>>(z0, 128, proj_W2, 128, proj_b2, NE,
                                           (float*)d_out, nullptr, 128, nullptr, nullptr);
}